// Round 10
// baseline (352.234 us; speedup 1.0000x reference)
//
#include <hip/hip_runtime.h>
#include <hip/hip_bf16.h>

typedef __bf16 bf16_t;
typedef __bf16 bf16x4 __attribute__((ext_vector_type(4)));
typedef __bf16 bf16x8 __attribute__((ext_vector_type(8)));
typedef float f32x4 __attribute__((ext_vector_type(4)));
typedef float f32x16 __attribute__((ext_vector_type(16)));

#define LN_EPS 1e-6f

__device__ __forceinline__ void gl2lds16(const void* g, void* l) {
    __builtin_amdgcn_global_load_lds(
        (const __attribute__((address_space(1))) void*)g,
        (__attribute__((address_space(3))) void*)l, 16, 0, 0);
}

// raw barrier (does NOT drain vmcnt, unlike __syncthreads) + compiler memory fence
__device__ __forceinline__ void block_sync() {
    __asm__ __volatile__("" ::: "memory");
    __builtin_amdgcn_s_barrier();
    __asm__ __volatile__("" ::: "memory");
}

// ---------------- LN body (vectorized bf16x4 store) ----------------
__device__ __forceinline__ void ln_row(const float* __restrict__ x, const float* __restrict__ g,
                                       const float* __restrict__ bb, bf16_t* __restrict__ out,
                                       int row, int t, float* sbuf, float* sbuf2) {
    const int D = 1024;
    const float4* xr = reinterpret_cast<const float4*>(x + (size_t)row * D);
    float4 v = xr[t];
    float s = v.x + v.y + v.z + v.w;
    int wave = t >> 6, lane = t & 63;
#pragma unroll
    for (int o = 32; o > 0; o >>= 1) s += __shfl_xor(s, o);
    if (lane == 0) sbuf[wave] = s;
    __syncthreads();
    float mean = (sbuf[0] + sbuf[1] + sbuf[2] + sbuf[3]) / (float)D;
    float d0 = v.x - mean, d1 = v.y - mean, d2 = v.z - mean, d3 = v.w - mean;
    float sq = d0 * d0 + d1 * d1 + d2 * d2 + d3 * d3;
#pragma unroll
    for (int o = 32; o > 0; o >>= 1) sq += __shfl_xor(sq, o);
    if (lane == 0) sbuf2[wave] = sq;
    __syncthreads();
    float var = (sbuf2[0] + sbuf2[1] + sbuf2[2] + sbuf2[3]) / (float)D;
    float inv = rsqrtf(var + LN_EPS);
    float4 gv = reinterpret_cast<const float4*>(g)[t];
    float4 bv = reinterpret_cast<const float4*>(bb)[t];
    bf16x4 o4;
    o4[0] = (bf16_t)(d0 * inv * gv.x + bv.x);
    o4[1] = (bf16_t)(d1 * inv * gv.y + bv.y);
    o4[2] = (bf16_t)(d2 * inv * gv.z + bv.z);
    o4[3] = (bf16_t)(d3 * inv * gv.w + bv.w);
    *reinterpret_cast<bf16x4*>(out + (size_t)row * D + t * 4) = o4;
}

// ---------------- fused weight prep + LN1: one launch ----
__global__ void prep_weights_kernel(const float* __restrict__ wq, const float* __restrict__ wk,
                                    const float* __restrict__ wv, const float* __restrict__ wo,
                                    const float* __restrict__ w1, const float* __restrict__ w3,
                                    const float* __restrict__ w2, bf16_t* __restrict__ wq_t,
                                    bf16_t* __restrict__ wk_t, bf16_t* __restrict__ wv_t,
                                    bf16_t* __restrict__ wo_t, bf16_t* __restrict__ w13_t,
                                    bf16_t* __restrict__ w2_t, const float* __restrict__ hs,
                                    const float* __restrict__ ln1g, const float* __restrict__ ln1b,
                                    bf16_t* __restrict__ x_b) {
    __shared__ float tile[32][33];
    __shared__ float sbuf[4];
    __shared__ float sbuf2[4];
    int id = blockIdx.x;
    if (id >= 16384) {
        ln_row(hs, ln1g, ln1b, x_b, id - 16384, threadIdx.x, sbuf, sbuf2);
        return;
    }
    const float* src;
    bf16_t* dst;
    int R, C, mode = 0;  // mode: 0 plain, 1 w1-interleave, 2 w3-interleave
    if (id < 4096) {
        int w = id >> 10;
        id &= 1023;
        src = (w == 0) ? wq : (w == 1) ? wk : (w == 2) ? wv : wo;
        dst = (w == 0) ? wq_t : (w == 1) ? wk_t : (w == 2) ? wv_t : wo_t;
        R = 1024; C = 1024;
    } else if (id < 8192) {
        id -= 4096; src = w1; dst = w13_t; R = 1024; C = 4096; mode = 1;
    } else if (id < 12288) {
        id -= 8192; src = w3; dst = w13_t; R = 1024; C = 4096; mode = 2;
    } else {
        id -= 12288; src = w2; dst = w2_t; R = 4096; C = 1024;
    }
    int tpc = C >> 5;
    int bx = id % tpc, by = id / tpc;
    int r0 = by * 32, c0 = bx * 32;
    int tx = threadIdx.x & 31;
    int ty = threadIdx.x >> 5;
#pragma unroll
    for (int i = 0; i < 4; i++) {
        int r = ty + i * 8;
        tile[r][tx] = src[(size_t)(r0 + r) * C + (c0 + tx)];
    }
    __syncthreads();
#pragma unroll
    for (int i = 0; i < 4; i++) {
        int r = ty + i * 8;
        int rr = c0 + r;
        if (mode) rr = ((rr >> 7) << 8) + (rr & 127) + ((mode == 2) ? 128 : 0);
        dst[(size_t)rr * R + (r0 + tx)] = (bf16_t)tile[tx][r];
    }
}

// ---------------- LayerNorm (fp32 in) -> bf16 out (kept for LN2) ----------------
__global__ void ln_kernel(const float* __restrict__ x, const float* __restrict__ g,
                          const float* __restrict__ bb, bf16_t* __restrict__ out, int D) {
    __shared__ float sbuf[4];
    __shared__ float sbuf2[4];
    ln_row(x, g, bb, out, blockIdx.x, threadIdx.x, sbuf, sbuf2);
}

// ---------------- gemm4 (kept for Wo): 128x128, single-buffer, BK=64, conflict-free ----------------
#define G4_BK 64

template <int EPI>
__launch_bounds__(256, 2) __global__
void gemm4_kernel(const bf16_t* __restrict__ A, const bf16_t* __restrict__ Bt,
                  float* __restrict__ Cf, const float* __restrict__ aux,
                  const bf16_t* __restrict__ auxb, bf16_t* __restrict__ Cb,
                  int M, int N, int K, int lda, int ldb) {
    __shared__ __align__(16) bf16_t As[128 * G4_BK];  // 16 KB
    __shared__ __align__(16) bf16_t Bs[128 * G4_BK];  // 16 KB
    const int t = threadIdx.x;
    const int wave = t >> 6, lane = t & 63;
    const int lr = lane & 15, quad = lane >> 4;
    const int wm = (wave >> 1) * 64, wn = (wave & 1) * 64;

    const int gx = gridDim.x, gy = gridDim.y;
    const int nwg = gx * gy;
    const int lin = blockIdx.y * gx + blockIdx.x;
    const int qch = nwg >> 3;
    const int sw = (lin & 7) * qch + (lin >> 3);
    const int m0 = (sw / gy) * 128;
    const int n0 = (sw % gy) * 128;
    const int koff = blockIdx.z * K;

    const int srow = t >> 3;
    const int sslot = (t & 7) ^ (srow & 7);
    const bf16_t* agp = A + (size_t)(m0 + srow) * lda + koff + sslot * 8;
    const bf16_t* bgp = Bt + (size_t)(n0 + srow) * ldb + koff + sslot * 8;
    bf16_t* asl = As + t * 8;
    bf16_t* bsl = Bs + t * 8;

    int aoff[4][2], boff[4][2];
#pragma unroll
    for (int f = 0; f < 4; f++)
#pragma unroll
        for (int s = 0; s < 2; s++) {
            int ra = wm + f * 16 + lr;
            int rb = wn + f * 16 + lr;
            aoff[f][s] = ra * G4_BK + (((s * 4 + quad) ^ (ra & 7)) << 3);
            boff[f][s] = rb * G4_BK + (((s * 4 + quad) ^ (rb & 7)) << 3);
        }

    f32x4 acc[4][4];
#pragma unroll
    for (int mi = 0; mi < 4; mi++)
#pragma unroll
        for (int ni = 0; ni < 4; ni++) acc[mi][ni] = 0.f;

    for (int k0 = 0; k0 < K; k0 += G4_BK) {
#pragma unroll
        for (int i = 0; i < 4; i++)
            gl2lds16(agp + k0 + (size_t)(32 * i) * lda, asl + i * 2048);
#pragma unroll
        for (int i = 0; i < 4; i++)
            gl2lds16(bgp + k0 + (size_t)(32 * i) * ldb, bsl + i * 2048);
        __syncthreads();
#pragma unroll
        for (int s = 0; s < 2; s++) {
            bf16x8 af[4], bfv[4];
#pragma unroll
            for (int mi = 0; mi < 4; mi++)
                af[mi] = *reinterpret_cast<const bf16x8*>(&As[aoff[mi][s]]);
#pragma unroll
            for (int ni = 0; ni < 4; ni++)
                bfv[ni] = *reinterpret_cast<const bf16x8*>(&Bs[boff[ni][s]]);
#pragma unroll
            for (int mi = 0; mi < 4; mi++)
#pragma unroll
                for (int ni = 0; ni < 4; ni++)
                    acc[mi][ni] = __builtin_amdgcn_mfma_f32_16x16x32_bf16(af[mi], bfv[ni],
                                                                          acc[mi][ni], 0, 0, 0);
        }
        __syncthreads();
    }

#pragma unroll
    for (int mi = 0; mi < 4; mi++)
#pragma unroll
        for (int ni = 0; ni < 4; ni++)
#pragma unroll
            for (int j = 0; j < 4; j++) {
                int gm = m0 + wm + mi * 16 + quad * 4 + j;
                int gn = n0 + wn + ni * 16 + lr;
                size_t idx = (size_t)gm * N + gn;
                float val = acc[mi][ni][j];
                if constexpr (EPI == 1) {
                    Cf[idx] = val + aux[idx];
                }
            }
}

// ---------------- gemm6 (16x16 MFMA; kept for QKV EPI 3 — RoPE pairing needs the
// within-wave (d, d+32) column strips): round-5 v1 schedule + 2D-XCD patches +
// hoisted incremental staging pointers.

template <int QM, int QN>
__device__ __forceinline__ void quad_mfma(f32x4 (&acc)[2][2][4][2], const bf16x8 (&af)[4][2],
                                          const bf16x8 (&bf)[2][2]) {
#pragma unroll
    for (int fr = 0; fr < 4; fr++)
#pragma unroll
        for (int fc = 0; fc < 2; fc++)
#pragma unroll
            for (int ks = 0; ks < 2; ks++)
                acc[QM][QN][fr][fc] = __builtin_amdgcn_mfma_f32_16x16x32_bf16(
                    af[fr][ks], bf[fc][ks], acc[QM][QN][fr][fc], 0, 0, 0);
}

template <int EPI>
__launch_bounds__(512, 2) __global__
void gemm6_kernel(const bf16_t* __restrict__ A, const bf16_t* __restrict__ Bt,
                  const bf16_t* __restrict__ auxb, bf16_t* __restrict__ Cb,
                  bf16_t* __restrict__ Cb2, int M, int N, int K, int lda, int ldb) {
    extern __shared__ __align__(16) bf16_t smem[];  // 128 KiB dynamic
    bf16_t* smA = smem;           // [2 buf][2 half][8192]
    bf16_t* smB = smem + 32768;   // [2 buf][2 half][8192]
    const int t = threadIdx.x;
    const int wave = t >> 6, lane = t & 63;
    const int lr = lane & 15, quad = lane >> 4;
    const int rowgrp = wave >> 2;
    const int colgrp = wave & 3;
    const int cg1 = colgrp & 1, cg2 = colgrp >> 1;

    const int gx = gridDim.x, gy = gridDim.y;
    const int nwg = gx * gy;
    const int lin = blockIdx.y * gx + blockIdx.x;
    int m0t, n0t;
    if (gy == 12) {
        // QKV (16m x 12n, 192 blocks all-resident): XCD grid 4m x 2n; patch 4m x 6n.
        int x = lin & 7, j = lin >> 3;
        m0t = (x & 3) * 4 + j / 6;
        n0t = (x >> 2) * 6 + j % 6;
    } else {
        const int qch = nwg >> 3;
        const int sw = (lin & 7) * qch + (lin >> 3);
        m0t = sw / gy;
        n0t = sw % gy;
    }
    const int m0 = m0t * 256;
    const int n0 = n0t * 256;
    const int koff = blockIdx.z * K;

    const bf16_t* Ag = A + (size_t)m0 * lda + koff;
    const bf16_t* Bg = Bt + (size_t)n0 * ldb + koff;

    // hoisted per-thread staging state: 4 halves x 2 loads, incremental (+64/use)
    const int li0 = (wave * 2 + 0) * 64 + lane;
    const int li1 = (wave * 2 + 1) * 64 + lane;
    const int r0s = li0 >> 3, c0s = ((li0 & 7) ^ (r0s & 7)) << 3;
    const int r1s = li1 >> 3, c1s = ((li1 & 7) ^ (r1s & 7)) << 3;
    const bf16_t* pA0[2] = {Ag + (size_t)r0s * lda + c0s, Ag + (size_t)r1s * lda + c1s};
    const bf16_t* pA1[2] = {pA0[0] + (size_t)128 * lda, pA0[1] + (size_t)128 * lda};
    const bf16_t* pB0[2] = {Bg + (size_t)r0s * ldb + c0s, Bg + (size_t)r1s * ldb + c1s};
    const bf16_t* pB1[2] = {pB0[0] + (size_t)128 * ldb, pB0[1] + (size_t)128 * ldb};
    const int dl0 = (wave * 2 + 0) * 512;
    const int dl1 = (wave * 2 + 1) * 512;

#define STG(P, LBASE)                          \
    do {                                       \
        gl2lds16(P[0], (LBASE) + dl0);         \
        P[0] += 64;                            \
        gl2lds16(P[1], (LBASE) + dl1);         \
        P[1] += 64;                            \
    } while (0)

    int aoff[4][2], boff[2][2];
#pragma unroll
    for (int fr = 0; fr < 4; fr++)
#pragma unroll
        for (int ks = 0; ks < 2; ks++) {
            int ra = rowgrp * 64 + fr * 16 + lr;
            aoff[fr][ks] = ra * 64 + (((ks * 4 + quad) ^ (ra & 7)) << 3);
        }
#pragma unroll
    for (int fc = 0; fc < 2; fc++)
#pragma unroll
        for (int ks = 0; ks < 2; ks++) {
            int rb = cg1 * 64 + cg2 * 16 + fc * 32 + lr;
            boff[fc][ks] = rb * 64 + (((ks * 4 + quad) ^ (rb & 7)) << 3);
        }

    f32x4 acc[2][2][4][2];
#pragma unroll
    for (int qm = 0; qm < 2; qm++)
#pragma unroll
        for (int qn = 0; qn < 2; qn++)
#pragma unroll
            for (int fr = 0; fr < 4; fr++)
#pragma unroll
                for (int fc = 0; fc < 2; fc++) acc[qm][qn][fr][fc] = 0.f;

    const int NT = K >> 6;

    STG(pA0, smA);
    STG(pB0, smB);
    STG(pB1, smB + 8192);
    STG(pA1, smA + 8192);
    if (NT > 1) {
        STG(pA0, smA + 16384);
        __asm__ __volatile__("s_waitcnt vmcnt(2)" ::: "memory");
    } else {
        __asm__ __volatile__("s_waitcnt vmcnt(0)" ::: "memory");
    }
    block_sync();

    bf16x8 af[4][2], bf0[2][2], bf1[2][2];

    for (int tt = 0; tt < NT; ++tt) {
        const int cur = tt & 1, nxt = cur ^ 1;
        const bf16_t* A0b = smA + cur * 16384;
        const bf16_t* A1b = A0b + 8192;
        const bf16_t* B0b = smB + cur * 16384;
        const bf16_t* B1b = B0b + 8192;
        bf16_t* sAn = smA + nxt * 16384;
        bf16_t* sBn = smB + nxt * 16384;
        bf16_t* sAc = smA + cur * 16384;
        const bool pf1 = (tt + 1 < NT);
        const bool pf2 = (tt + 2 < NT);

        // ---- ph0
#pragma unroll
        for (int fr = 0; fr < 4; fr++)
#pragma unroll
            for (int ks = 0; ks < 2; ks++)
                af[fr][ks] = *reinterpret_cast<const bf16x8*>(A0b + aoff[fr][ks]);
#pragma unroll
        for (int fc = 0; fc < 2; fc++)
#pragma unroll
            for (int ks = 0; ks < 2; ks++)
                bf0[fc][ks] = *reinterpret_cast<const bf16x8*>(B0b + boff[fc][ks]);
        if (pf1) STG(pB0, sBn);
        block_sync();
        __asm__ __volatile__("s_waitcnt lgkmcnt(0)" ::: "memory");
        __builtin_amdgcn_sched_barrier(0);
        __builtin_amdgcn_s_setprio(1);
        quad_mfma<0, 0>(acc, af, bf0);
        __builtin_amdgcn_s_setprio(0);
        block_sync();

        // ---- ph1
#pragma unroll
        for (int fc = 0; fc < 2; fc++)
#pragma unroll
            for (int ks = 0; ks < 2; ks++)
                bf1[fc][ks] = *reinterpret_cast<const bf16x8*>(B1b + boff[fc][ks]);
        if (pf1) STG(pB1, sBn + 8192);
        block_sync();
        __asm__ __volatile__("s_waitcnt lgkmcnt(0)" ::: "memory");
        __builtin_amdgcn_sched_barrier(0);
        __builtin_amdgcn_s_setprio(1);
        quad_mfma<0, 1>(acc, af, bf1);
        __builtin_amdgcn_s_setprio(0);
        block_sync();

        // ---- ph2
#pragma unroll
        for (int fr = 0; fr < 4; fr++)
#pragma unroll
            for (int ks = 0; ks < 2; ks++)
                af[fr][ks] = *reinterpret_cast<const bf16x8*>(A1b + aoff[fr][ks]);
        if (pf1) STG(pA1, sAn + 8192);
        block_sync();
        __asm__ __volatile__("s_waitcnt lgkmcnt(0)" ::: "memory");
        __builtin_amdgcn_sched_barrier(0);
        __builtin_amdgcn_s_setprio(1);
        quad_mfma<1, 1>(acc, af, bf1);
        __builtin_amdgcn_s_setprio(0);
        block_sync();

        // ---- ph3
        if (pf2) STG(pA0, sAc);
        __builtin_amdgcn_s_setprio(1);
        quad_mfma<1, 0>(acc, af, bf0);
        __builtin_amdgcn_s_setprio(0);
        __asm__ __volatile__("s_waitcnt vmcnt(2)" ::: "memory");
        block_sync();
    }
#undef STG

    // C/D 16x16 layout: col=lane&15, row=quad*4+reg
    if constexpr (EPI == 3) {
        if (n0 < 2048) {
            const float kfreq = -0.41524101186f;  // -log2(10000)/32
            const int d = cg2 * 16 + lr;          // head-dim of fc=0 element, in [0,32)
            const float freq = exp2f((float)d * kfreq);
#pragma unroll
            for (int qm = 0; qm < 2; qm++)
#pragma unroll
                for (int qn = 0; qn < 2; qn++) {
                    const int gnb = n0 + qn * 128 + cg1 * 64;
#pragma unroll
                    for (int fr = 0; fr < 4; fr++)
#pragma unroll
                        for (int j = 0; j < 4; j++) {
                            int gm = m0 + qm * 128 + rowgrp * 64 + fr * 16 + quad * 4 + j;
                            float pos = (float)(gm & 2047);
                            float ang = pos * freq;
                            float sn, cs;
                            __sincosf(ang, &sn, &cs);
                            float x1 = acc[qm][qn][fr][0][j];
                            float x2 = acc[qm][qn][fr][1][j];
                            size_t idx = (size_t)gm * N + gnb + d;
                            Cb[idx] = (bf16_t)(x1 * cs - x2 * sn);
                            Cb[idx + 32] = (bf16_t)(x2 * cs + x1 * sn);
                        }
                }
        } else {
            // V columns: write direct-transposed into vt [B,H,64,S], packed 4 rows (s)
#pragma unroll
            for (int qm = 0; qm < 2; qm++)
#pragma unroll
                for (int qn = 0; qn < 2; qn++)
#pragma unroll
                    for (int fr = 0; fr < 4; fr++)
#pragma unroll
                        for (int fc = 0; fc < 2; fc++) {
                            int gmb = m0 + qm * 128 + rowgrp * 64 + fr * 16 + quad * 4;
                            int vcol = (n0 - 2048) + qn * 128 + cg1 * 64 + cg2 * 16 + fc * 32 + lr;
                            int hh = vcol >> 6, dd = vcol & 63;
                            int bb2 = gmb >> 11, ss = gmb & 2047;
                            bf16x4 pk;
#pragma unroll
                            for (int j = 0; j < 4; j++) pk[j] = (bf16_t)acc[qm][qn][fr][fc][j];
                            *reinterpret_cast<bf16x4*>(
                                &Cb2[(((size_t)(bb2 * 16 + hh)) * 64 + dd) * 2048 + ss]) = pk;
                        }
        }
    }
}

// ---------------- gemm7 (32x32x16 MFMA; W13 + W2): same schedule/staging/swizzle/XCD
// machinery as gemm6, but 32x32 fragments: +15% matrix-pipe rate (m119: 2495 vs 2176 TF),
// half the MFMA instruction count. A-frag: row=lane&31, k=(lane>>5)*8; B same; C/D:
// col=lane&31, row=(reg&3)+8*(reg>>2)+4*(lane>>5)  [m74/m101 verified].
// Wave: 128 rows x 64 cols per (qm,qn) pair: 2 m-frags x 1 n-frag (wn = wave&3).
// EPI 5: split-K partial ; EPI 6: fused W1|W3 interleaved -> silu(a)*b

template <int QM, int QN>
__device__ __forceinline__ void quad_mfma32(f32x16 (&acc)[2][2][2], const bf16x8 (&af)[2][4],
                                            const bf16x8 (&bf)[4]) {
#pragma unroll
    for (int ks = 0; ks < 4; ks++)
#pragma unroll
        for (int mf = 0; mf < 2; mf++)
            acc[QM][QN][mf] = __builtin_amdgcn_mfma_f32_32x32x16_bf16(
                af[mf][ks], bf[ks], acc[QM][QN][mf], 0, 0, 0);
}

template <int EPI>
__launch_bounds__(512, 2) __global__
void gemm7_kernel(const bf16_t* __restrict__ A, const bf16_t* __restrict__ Bt,
                  bf16_t* __restrict__ Cb, int M, int N, int K, int lda, int ldb) {
    extern __shared__ __align__(16) bf16_t smem[];  // 128 KiB dynamic
    bf16_t* smA = smem;           // [2 buf][2 half][8192]
    bf16_t* smB = smem + 32768;   // [2 buf][2 half][8192]
    const int t = threadIdx.x;
    const int wave = t >> 6, lane = t & 63;
    const int l31 = lane & 31, lh = lane >> 5;
    const int rowgrp = wave >> 2;   // 0..1: 64-row group within 128-row half
    const int wn = wave & 3;        // 0..3: 32-col group within 128-col half

    const int gx = gridDim.x, gy = gridDim.y;
    const int nwg = gx * gy;
    const int lin = blockIdx.y * gx + blockIdx.x;
    int m0t, n0t;
    if (gy == 32) {
        // W13 (16m x 32n): supergroup 256 = 8m x 32n; XCD grid 2m x 4n; patch 4m x 8n.
        int s = lin >> 8, r = lin & 255, x = r & 7, j = r >> 3;
        m0t = s * 8 + (x & 1) * 4 + (j >> 3);
        n0t = (x >> 1) * 8 + (j & 7);
    } else {
        const int qch = nwg >> 3;
        const int sw = (lin & 7) * qch + (lin >> 3);
        m0t = sw / gy;
        n0t = sw % gy;
    }
    const int m0 = m0t * 256;
    const int n0 = n0t * 256;
    const int koff = blockIdx.z * K;

    const bf16_t* Ag = A + (size_t)m0 * lda + koff;
    const bf16_t* Bg = Bt + (size_t)n0 * ldb + koff;

    const int li0 = (wave * 2 + 0) * 64 + lane;
    const int li1 = (wave * 2 + 1) * 64 + lane;
    const int r0s = li0 >> 3, c0s = ((li0 & 7) ^ (r0s & 7)) << 3;
    const int r1s = li1 >> 3, c1s = ((li1 & 7) ^ (r1s & 7)) << 3;
    const bf16_t* pA0[2] = {Ag + (size_t)r0s * lda + c0s, Ag + (size_t)r1s * lda + c1s};
    const bf16_t* pA1[2] = {pA0[0] + (size_t)128 * lda, pA0[1] + (size_t)128 * lda};
    const bf16_t* pB0[2] = {Bg + (size_t)r0s * ldb + c0s, Bg + (size_t)r1s * ldb + c1s};
    const bf16_t* pB1[2] = {pB0[0] + (size_t)128 * ldb, pB0[1] + (size_t)128 * ldb};
    const int dl0 = (wave * 2 + 0) * 512;
    const int dl1 = (wave * 2 + 1) * 512;

#define STG(P, LBASE)                          \
    do {                                       \
        gl2lds16(P[0], (LBASE) + dl0);         \
        P[0] += 64;                            \
        gl2lds16(P[1], (LBASE) + dl1);         \
        P[1] += 64;                            \
    } while (0)

    // swizzled LDS read offsets: slot = (ks*2 + lh) ^ (row&7); every aligned 8-lane
    // group covers 8 distinct 16B slots -> conflict-free (same mechanism as gemm6).
    int aoff[2][4], boff[4];
#pragma unroll
    for (int mf = 0; mf < 2; mf++)
#pragma unroll
        for (int ks = 0; ks < 4; ks++) {
            int ra = rowgrp * 64 + mf * 32 + l31;
            aoff[mf][ks] = ra * 64 + (((ks * 2 + lh) ^ (ra & 7)) << 3);
        }
#pragma unroll
    for (int ks = 0; ks < 4; ks++) {
        int rb = wn * 32 + l31;
        boff[ks] = rb * 64 + (((ks * 2 + lh) ^ (rb & 7)) << 3);
    }

    f32x16 acc[2][2][2];
#pragma unroll
    for (int qm = 0; qm < 2; qm++)
#pragma unroll
        for (int qn = 0; qn < 2; qn++)
#pragma unroll
            for (int mf = 0; mf < 2; mf++) acc[qm][qn][mf] = 0.f;

    const int NT = K >> 6;

    STG(pA0, smA);
    STG(pB0, smB);
    STG(pB1, smB + 8192);
    STG(pA1, smA + 8192);
    if (NT > 1) {
        STG(pA0, smA + 16384);
        __asm__ __volatile__("s_waitcnt vmcnt(2)" ::: "memory");
    } else {
        __asm__ __volatile__("s_waitcnt vmcnt(0)" ::: "memory");
    }
    block_sync();

    bf16x8 af[2][4], bf0[4], bf1[4];

    for (int tt = 0; tt < NT; ++tt) {
        const int cur = tt & 1, nxt = cur ^ 1;
        const bf16_t* A0b = smA + cur * 16384;
        const bf16_t* A1b = A0b + 8192;
        const bf16_t* B0b = smB + cur * 16384;
        const bf16_t* B1b = B0b + 8192;
        bf16_t* sAn = smA + nxt * 16384;
        bf16_t* sBn = smB + nxt * 16384;
        bf16_t* sAc = smA + cur * 16384;
        const bool pf1 = (tt + 1 < NT);
        const bool pf2 = (tt + 2 < NT);

        // ---- ph0: read A0 frags + B0 frags; stage B0(t+1); MFMA q00
#pragma unroll
        for (int mf = 0; mf < 2; mf++)
#pragma unroll
            for (int ks = 0; ks < 4; ks++)
                af[mf][ks] = *reinterpret_cast<const bf16x8*>(A0b + aoff[mf][ks]);
#pragma unroll
        for (int ks = 0; ks < 4; ks++)
            bf0[ks] = *reinterpret_cast<const bf16x8*>(B0b + boff[ks]);
        if (pf1) STG(pB0, sBn);
        block_sync();
        __asm__ __volatile__("s_waitcnt lgkmcnt(0)" ::: "memory");
        __builtin_amdgcn_sched_barrier(0);
        __builtin_amdgcn_s_setprio(1);
        quad_mfma32<0, 0>(acc, af, bf0);
        __builtin_amdgcn_s_setprio(0);
        block_sync();

        // ---- ph1: read B1 frags; stage B1(t+1); MFMA q01
#pragma unroll
        for (int ks = 0; ks < 4; ks++)
            bf1[ks] = *reinterpret_cast<const bf16x8*>(B1b + boff[ks]);
        if (pf1) STG(pB1, sBn + 8192);
        block_sync();
        __asm__ __volatile__("s_waitcnt lgkmcnt(0)" ::: "memory");
        __builtin_amdgcn_sched_barrier(0);
        __builtin_amdgcn_s_setprio(1);
        quad_mfma32<0, 1>(acc, af, bf1);
        __builtin_amdgcn_s_setprio(0);
        block_sync();

        // ---- ph2: read A1 frags (overwrite af); stage A1(t+1); MFMA q11
#pragma unroll
        for (int mf = 0; mf < 2; mf++)
#pragma unroll
            for (int ks = 0; ks < 4; ks++)
                af[mf][ks] = *reinterpret_cast<const bf16x8*>(A1b + aoff[mf][ks]);
        if (pf1) STG(pA1, sAn + 8192);
        block_sync();
        __asm__ __volatile__("s_waitcnt lgkmcnt(0)" ::: "memory");
        __builtin_amdgcn_sched_barrier(0);
        __builtin_amdgcn_s_setprio(1);
        quad_mfma32<1, 1>(acc, af, bf1);
        __builtin_amdgcn_s_setprio(0);
        block_sync();

        // ---- ph3: stage A0(t+2); MFMA q10 (regs only); single vmcnt(2) per tile
        if (pf2) STG(pA0, sAc);
        __builtin_amdgcn_s_setprio(1);
        quad_mfma32<1, 0>(acc, af, bf0);
        __builtin_amdgcn_s_setprio(0);
        __asm__ __volatile__("s_waitcnt vmcnt(2)" ::: "memory");
        block_sync();
    }
#undef STG

    // C/D 32x32 layout: col = lane&31, row = (reg&3) + 8*(reg>>2) + 4*lh
    if constexpr (EPI == 6) {
        const int No = N >> 1;
        const int c = (n0 >> 1) + wn * 32 + l31;
#pragma unroll
        for (int qm = 0; qm < 2; qm++)
#pragma unroll
            for (int mf = 0; mf < 2; mf++)
#pragma unroll
                for (int reg = 0; reg < 16; reg++) {
                    int rrow = (reg & 3) + 8 * (reg >> 2) + 4 * lh;
                    int gm = m0 + qm * 128 + rowgrp * 64 + mf * 32 + rrow;
                    float a = acc[qm][0][mf][reg];
                    float bv = acc[qm][1][mf][reg];
                    float sl = a / (1.0f + __expf(-a));
                    Cb[(size_t)gm * No + c] = (bf16_t)(sl * bv);
                }
    } else {
        size_t outoff = (EPI == 5) ? (size_t)blockIdx.z * M * N : 0;
#pragma unroll
        for (int qm = 0; qm < 2; qm++)
#pragma unroll
            for (int qn = 0; qn < 2; qn++) {
                const int gn = n0 + qn * 128 + wn * 32 + l31;
#pragma unroll
                for (int mf = 0; mf < 2; mf++)
#pragma unroll
                    for (int reg = 0; reg < 16; reg++) {
                        int rrow = (reg & 3) + 8 * (reg >> 2) + 4 * lh;
                        int gm = m0 + qm * 128 + rowgrp * 64 + mf * 32 + rrow;
                        Cb[outoff + (size_t)gm * N + gn] = (bf16_t)acc[qm][qn][mf][reg];
                    }
            }
    }
}

// ---------------- split-K reduce + residual: out = hid + sum_c partial[c] ----------------
__global__ void reduce4_kernel(const bf16_t* __restrict__ p, const float* __restrict__ hid,
                               float* __restrict__ out, int n4) {
    int i = blockIdx.x * 256 + threadIdx.x;
    if (i >= n4) return;
    size_t i4 = (size_t)i * 4;
    float4 h = *reinterpret_cast<const float4*>(hid + i4);
    const size_t stride = (size_t)4096 * 1024;
#pragma unroll
    for (int c = 0; c < 4; c++) {
        bf16x4 a = *reinterpret_cast<const bf16x4*>(p + c * stride + i4);
        h.x += (float)a[0];
        h.y += (float)a[1];
        h.z += (float)a[2];
        h.w += (float)a[3];
    }
    *reinterpret_cast<float4*>(out + i4) = h;
}

// ---------------- MFMA sliding-window attention (17 K-tiles) ----------------
#define PSTR 40
#define QKVS 3072
__global__ __launch_bounds__(256, 2) void attn_kernel(const bf16_t* __restrict__ qkv,
                                                      const bf16_t* __restrict__ vt,
                                                      bf16_t* __restrict__ ctx, int S) {
    __shared__ __align__(16) bf16_t Pbuf[4][16 * PSTR];
    int t = threadIdx.x;
    int wave = t >> 6, lane = t & 63;
    int col = lane & 15, quad = lane >> 4;
    int h = blockIdx.y, b = blockIdx.z;
    int q0 = blockIdx.x * 64 + wave * 16;

    const bf16_t* qrow = qkv + (size_t)(b * S + q0 + col) * QKVS + h * 64;
    bf16x8 aq0 = *reinterpret_cast<const bf16x8*>(qrow + quad * 8);
    bf16x8 aq1 = *reinterpret_cast<const bf16x8*>(qrow + 32 + quad * 8);

    int jbase = q0 - 256;
    f32x4 sc[17];
#pragma unroll
    for (int kt = 0; kt < 17; kt++) {
        int j = jbase + kt * 16 + col;
        int jc = j < 0 ? 0 : (j > S - 1 ? S - 1 : j);
        const bf16_t* krow = qkv + (size_t)(b * S + jc) * QKVS + 1024 + h * 64;
        bf16x8 bk0 = *reinterpret_cast<const bf16x8*>(krow + quad * 8);
        bf16x8 bk1 = *reinterpret_cast<const bf16x8*>(krow + 32 + quad * 8);
        f32x4 c0 = {0.f, 0.f, 0.f, 0.f};
        c0 = __builtin_amdgcn_mfma_f32_16x16x32_bf16(aq0, bk0, c0, 0, 0, 0);
        c0 = __builtin_amdgcn_mfma_f32_16x16x32_bf16(aq1, bk1, c0, 0, 0, 0);
        sc[kt] = c0;
    }
#pragma unroll
    for (int kt = 0; kt < 17; kt++) {
#pragma unroll
        for (int jj = 0; jj < 4; jj++) {
            int qq = quad * 4 + jj;
            int j = jbase + kt * 16 + col;
            int rel = (q0 + qq) - j;
            bool ok = (j >= 0) && (rel >= 0) && (rel < 256);
            sc[kt][jj] = ok ? sc[kt][jj] * 0.125f : -1e30f;
        }
    }
    float sminv[4];
#pragma unroll
    for (int jj = 0; jj < 4; jj++) {
        float m = -1e30f;
#pragma unroll
        for (int kt = 0; kt < 17; kt++) m = fmaxf(m, sc[kt][jj]);
#pragma unroll
        for (int o = 1; o < 16; o <<= 1) m = fmaxf(m, __shfl_xor(m, o));
        float s = 0.f;
#pragma unroll
        for (int kt = 0; kt < 17; kt++) {
            float p = __expf(sc[kt][jj] - m);
            sc[kt][jj] = p;
            s += p;
        }
#pragma unroll
        for (int o = 1; o < 16; o <<= 1) s += __shfl_xor(s, o);
        sminv[jj] = 1.0f / s;
    }
    f32x4 o[4];
#pragma unroll
    for (int n = 0; n < 4; n++) o[n] = 0.f;
    bf16_t* myP = Pbuf[wave];
    const bf16_t* vplane = vt + ((size_t)(b * 16 + h)) * 64 * S;
#pragma unroll
    for (int c = 0; c < 9; c++) {
#pragma unroll
        for (int half = 0; half < 2; half++) {
            int kt = 2 * c + half;
#pragma unroll
            for (int jj = 0; jj < 4; jj++) {
                int qq = quad * 4 + jj;
                bf16_t pv = (kt < 17) ? (bf16_t)(sc[kt < 17 ? kt : 0][jj] * sminv[jj])
                                      : (bf16_t)0.f;
                myP[qq * PSTR + half * 16 + col] = pv;
            }
        }
        bf16x8 ap = *reinterpret_cast<const bf16x8*>(myP + col * PSTR + quad * 8);
        int key0 = jbase + c * 32 + quad * 8;
        int kc = key0 < 0 ? 0 : (key0 > S - 8 ? S - 8 : key0);
#pragma unroll
        for (int n = 0; n < 4; n++) {
            bf16x8 bv = *reinterpret_cast<const bf16x8*>(vplane + ((size_t)(n * 16 + col)) * S + kc);
            o[n] = __builtin_amdgcn_mfma_f32_16x16x32_bf16(ap, bv, o[n], 0, 0, 0);
        }
    }
#pragma unroll
    for (int n = 0; n < 4; n++)
#pragma unroll
        for (int jj = 0; jj < 4; jj++) {
            int qq = quad * 4 + jj;
            ctx[((size_t)(b * S + q0 + qq) * 16 + h) * 64 + n * 16 + col] = (bf16_t)o[n][jj];
        }
}

// ---------------- launch ----------------
extern "C" void kernel_launch(void* const* d_in, const int* in_sizes, int n_in,
                              void* d_out, int out_size, void* d_ws, size_t ws_size,
                              hipStream_t stream) {
    const float* hs   = (const float*)d_in[0];
    const float* wq   = (const float*)d_in[1];
    const float* wk   = (const float*)d_in[2];
    const float* wv   = (const float*)d_in[3];
    const float* wo   = (const float*)d_in[4];
    const float* w1   = (const float*)d_in[5];
    const float* w2   = (const float*)d_in[6];
    const float* w3   = (const float*)d_in[7];
    const float* ln1g = (const float*)d_in[8];
    const float* ln1b = (const float*)d_in[9];
    const float* ln2g = (const float*)d_in[10];
    const float* ln2b = (const float*)d_in[11];
    float* out = (float*)d_out;

    const int B = 2, S = 2048, D = 1024, I = 4096;
    const int BS = B * S;

    char* ws = (char*)d_ws;
    const size_t MB = 1024 * 1024;
    bf16_t* wq_t  = (bf16_t*)(ws + 0 * MB);    // 2MB
    bf16_t* wk_t  = (bf16_t*)(ws + 2 * MB);    // 2MB
    bf16_t* wv_t  = (bf16_t*)(ws + 4 * MB);    // 2MB
    bf16_t* wo_t  = (bf16_t*)(ws + 6 * MB);    // 2MB
    bf16_t* w13_t = (bf16_t*)(ws + 8 * MB);    // 16MB [8192,1024] interleaved
    bf16_t* w2_t  = (bf16_t*)(ws + 24 * MB);   // 8MB
    bf16_t* x_b   = (bf16_t*)(ws + 32 * MB);   // 8MB
    float*  hid   = (float*)(ws + 40 * MB);    // 16MB
    bf16_t* x2_b  = (bf16_t*)(ws + 56 * MB);   // 8MB
    bf16_t* qkvb  = (bf16_t*)(ws + 64 * MB);   // 24MB [BS,3072] (V section unused)
    bf16_t* vt    = (bf16_t*)(ws + 88 * MB);   // 8MB
    bf16_t* ctxb  = (bf16_t*)(ws + 96 * MB);   // 8MB
    bf16_t* hbuf  = (bf16_t*)(ws + 96 * MB);   // 32MB, aliases ctxb (dead post-Wo)
    bf16_t* pker  = (bf16_t*)(ws + 64 * MB);   // 32MB, aliases qkvb/vt (dead post-attn)

    hipFuncSetAttribute(reinterpret_cast<const void*>(&gemm6_kernel<3>),
                        hipFuncAttributeMaxDynamicSharedMemorySize, 131072);
    hipFuncSetAttribute(reinterpret_cast<const void*>(&gemm7_kernel<5>),
                        hipFuncAttributeMaxDynamicSharedMemorySize, 131072);
    hipFuncSetAttribute(reinterpret_cast<const void*>(&gemm7_kernel<6>),
                        hipFuncAttributeMaxDynamicSharedMemorySize, 131072);

    dim3 tb(256);
    dim3 tb6(512);

    // weight prep + LN1 in one launch
    prep_weights_kernel<<<dim3(20480), tb, 0, stream>>>(wq, wk, wv, wo, w1, w3, w2, wq_t, wk_t,
                                                        wv_t, wo_t, w13_t, w2_t, hs, ln1g, ln1b,
                                                        x_b);

    // fused QKV GEMM (RoPE for q,k cols; V written direct-transposed to vt) — 16x16 gemm6
    gemm6_kernel<3><<<dim3(BS / 256, 3072 / 256), tb6, 131072, stream>>>(
        x_b, wq_t, nullptr, qkvb, vt, BS, 3072, D, D, D);

    attn_kernel<<<dim3(S / 64, 16, B), tb, 0, stream>>>(qkvb, vt, ctxb, S);

    // Wo + residual (fp32 out)
    gemm4_kernel<1><<<dim3(BS / 128, D / 128), tb, 0, stream>>>(
        ctxb, wo_t, hid, hs, nullptr, nullptr, BS, D, D, D, D);

    ln_kernel<<<BS, tb, 0, stream>>>(hid, ln2g, ln2b, x2_b, D);

    // fused W1|W3 GEMM + silu*mul — 32x32 gemm7
    gemm7_kernel<6><<<dim3(BS / 256, 8192 / 256), tb6, 131072, stream>>>(
        x2_b, w13_t, hbuf, BS, 8192, D, D, D);

    // W2: split-K x4 — 32x32 gemm7, bf16 partials, then reduce + residual
    gemm7_kernel<5><<<dim3(BS / 256, D / 256, 4), tb6, 131072, stream>>>(
        hbuf, w2_t, pker, BS, D, 1024, I, I);
    reduce4_kernel<<<dim3(BS * D / 4 / 256), tb, 0, stream>>>(pker, hid, out, BS * D / 4);
}

// Round 11
// 339.258 us; speedup vs baseline: 1.0382x; 1.0382x over previous
//
#include <hip/hip_runtime.h>
#include <hip/hip_bf16.h>

typedef __bf16 bf16_t;
typedef __bf16 bf16x4 __attribute__((ext_vector_type(4)));
typedef __bf16 bf16x8 __attribute__((ext_vector_type(8)));
typedef float f32x4 __attribute__((ext_vector_type(4)));

#define LN_EPS 1e-6f

__device__ __forceinline__ void gl2lds16(const void* g, void* l) {
    __builtin_amdgcn_global_load_lds(
        (const __attribute__((address_space(1))) void*)g,
        (__attribute__((address_space(3))) void*)l, 16, 0, 0);
}

// raw barrier (does NOT drain vmcnt, unlike __syncthreads) + compiler memory fence
__device__ __forceinline__ void block_sync() {
    __asm__ __volatile__("" ::: "memory");
    __builtin_amdgcn_s_barrier();
    __asm__ __volatile__("" ::: "memory");
}

// ---------------- LN body (vectorized bf16x4 store) ----------------
__device__ __forceinline__ void ln_row(const float* __restrict__ x, const float* __restrict__ g,
                                       const float* __restrict__ bb, bf16_t* __restrict__ out,
                                       int row, int t, float* sbuf, float* sbuf2) {
    const int D = 1024;
    const float4* xr = reinterpret_cast<const float4*>(x + (size_t)row * D);
    float4 v = xr[t];
    float s = v.x + v.y + v.z + v.w;
    int wave = t >> 6, lane = t & 63;
#pragma unroll
    for (int o = 32; o > 0; o >>= 1) s += __shfl_xor(s, o);
    if (lane == 0) sbuf[wave] = s;
    __syncthreads();
    float mean = (sbuf[0] + sbuf[1] + sbuf[2] + sbuf[3]) / (float)D;
    float d0 = v.x - mean, d1 = v.y - mean, d2 = v.z - mean, d3 = v.w - mean;
    float sq = d0 * d0 + d1 * d1 + d2 * d2 + d3 * d3;
#pragma unroll
    for (int o = 32; o > 0; o >>= 1) sq += __shfl_xor(sq, o);
    if (lane == 0) sbuf2[wave] = sq;
    __syncthreads();
    float var = (sbuf2[0] + sbuf2[1] + sbuf2[2] + sbuf2[3]) / (float)D;
    float inv = rsqrtf(var + LN_EPS);
    float4 gv = reinterpret_cast<const float4*>(g)[t];
    float4 bv = reinterpret_cast<const float4*>(bb)[t];
    bf16x4 o4;
    o4[0] = (bf16_t)(d0 * inv * gv.x + bv.x);
    o4[1] = (bf16_t)(d1 * inv * gv.y + bv.y);
    o4[2] = (bf16_t)(d2 * inv * gv.z + bv.z);
    o4[3] = (bf16_t)(d3 * inv * gv.w + bv.w);
    *reinterpret_cast<bf16x4*>(out + (size_t)row * D + t * 4) = o4;
}

// ---------------- fused weight prep + LN1: one launch ----
__global__ void prep_weights_kernel(const float* __restrict__ wq, const float* __restrict__ wk,
                                    const float* __restrict__ wv, const float* __restrict__ wo,
                                    const float* __restrict__ w1, const float* __restrict__ w3,
                                    const float* __restrict__ w2, bf16_t* __restrict__ wq_t,
                                    bf16_t* __restrict__ wk_t, bf16_t* __restrict__ wv_t,
                                    bf16_t* __restrict__ wo_t, bf16_t* __restrict__ w13_t,
                                    bf16_t* __restrict__ w2_t, const float* __restrict__ hs,
                                    const float* __restrict__ ln1g, const float* __restrict__ ln1b,
                                    bf16_t* __restrict__ x_b) {
    __shared__ float tile[32][33];
    __shared__ float sbuf[4];
    __shared__ float sbuf2[4];
    int id = blockIdx.x;
    if (id >= 16384) {
        ln_row(hs, ln1g, ln1b, x_b, id - 16384, threadIdx.x, sbuf, sbuf2);
        return;
    }
    const float* src;
    bf16_t* dst;
    int R, C, mode = 0;  // mode: 0 plain, 1 w1-interleave, 2 w3-interleave
    if (id < 4096) {
        int w = id >> 10;
        id &= 1023;
        src = (w == 0) ? wq : (w == 1) ? wk : (w == 2) ? wv : wo;
        dst = (w == 0) ? wq_t : (w == 1) ? wk_t : (w == 2) ? wv_t : wo_t;
        R = 1024; C = 1024;
    } else if (id < 8192) {
        id -= 4096; src = w1; dst = w13_t; R = 1024; C = 4096; mode = 1;
    } else if (id < 12288) {
        id -= 8192; src = w3; dst = w13_t; R = 1024; C = 4096; mode = 2;
    } else {
        id -= 12288; src = w2; dst = w2_t; R = 4096; C = 1024;
    }
    int tpc = C >> 5;
    int bx = id % tpc, by = id / tpc;
    int r0 = by * 32, c0 = bx * 32;
    int tx = threadIdx.x & 31;
    int ty = threadIdx.x >> 5;
#pragma unroll
    for (int i = 0; i < 4; i++) {
        int r = ty + i * 8;
        tile[r][tx] = src[(size_t)(r0 + r) * C + (c0 + tx)];
    }
    __syncthreads();
#pragma unroll
    for (int i = 0; i < 4; i++) {
        int r = ty + i * 8;
        int rr = c0 + r;
        if (mode) rr = ((rr >> 7) << 8) + (rr & 127) + ((mode == 2) ? 128 : 0);
        dst[(size_t)rr * R + (r0 + tx)] = (bf16_t)tile[tx][r];
    }
}

// ---------------- LayerNorm (fp32 in) -> bf16 out (kept for LN2) ----------------
__global__ void ln_kernel(const float* __restrict__ x, const float* __restrict__ g,
                          const float* __restrict__ bb, bf16_t* __restrict__ out, int D) {
    __shared__ float sbuf[4];
    __shared__ float sbuf2[4];
    ln_row(x, g, bb, out, blockIdx.x, threadIdx.x, sbuf, sbuf2);
}

// ---------------- gemm4 (kept for Wo): 128x128, single-buffer, BK=64, conflict-free ----------------
#define G4_BK 64

template <int EPI>
__launch_bounds__(256, 2) __global__
void gemm4_kernel(const bf16_t* __restrict__ A, const bf16_t* __restrict__ Bt,
                  float* __restrict__ Cf, const float* __restrict__ aux,
                  const bf16_t* __restrict__ auxb, bf16_t* __restrict__ Cb,
                  int M, int N, int K, int lda, int ldb) {
    __shared__ __align__(16) bf16_t As[128 * G4_BK];  // 16 KB
    __shared__ __align__(16) bf16_t Bs[128 * G4_BK];  // 16 KB
    const int t = threadIdx.x;
    const int wave = t >> 6, lane = t & 63;
    const int lr = lane & 15, quad = lane >> 4;
    const int wm = (wave >> 1) * 64, wn = (wave & 1) * 64;

    const int gx = gridDim.x, gy = gridDim.y;
    const int nwg = gx * gy;
    const int lin = blockIdx.y * gx + blockIdx.x;
    const int qch = nwg >> 3;
    const int sw = (lin & 7) * qch + (lin >> 3);
    const int m0 = (sw / gy) * 128;
    const int n0 = (sw % gy) * 128;
    const int koff = blockIdx.z * K;

    const int srow = t >> 3;
    const int sslot = (t & 7) ^ (srow & 7);
    const bf16_t* agp = A + (size_t)(m0 + srow) * lda + koff + sslot * 8;
    const bf16_t* bgp = Bt + (size_t)(n0 + srow) * ldb + koff + sslot * 8;
    bf16_t* asl = As + t * 8;
    bf16_t* bsl = Bs + t * 8;

    int aoff[4][2], boff[4][2];
#pragma unroll
    for (int f = 0; f < 4; f++)
#pragma unroll
        for (int s = 0; s < 2; s++) {
            int ra = wm + f * 16 + lr;
            int rb = wn + f * 16 + lr;
            aoff[f][s] = ra * G4_BK + (((s * 4 + quad) ^ (ra & 7)) << 3);
            boff[f][s] = rb * G4_BK + (((s * 4 + quad) ^ (rb & 7)) << 3);
        }

    f32x4 acc[4][4];
#pragma unroll
    for (int mi = 0; mi < 4; mi++)
#pragma unroll
        for (int ni = 0; ni < 4; ni++) acc[mi][ni] = 0.f;

    for (int k0 = 0; k0 < K; k0 += G4_BK) {
#pragma unroll
        for (int i = 0; i < 4; i++)
            gl2lds16(agp + k0 + (size_t)(32 * i) * lda, asl + i * 2048);
#pragma unroll
        for (int i = 0; i < 4; i++)
            gl2lds16(bgp + k0 + (size_t)(32 * i) * ldb, bsl + i * 2048);
        __syncthreads();
#pragma unroll
        for (int s = 0; s < 2; s++) {
            bf16x8 af[4], bfv[4];
#pragma unroll
            for (int mi = 0; mi < 4; mi++)
                af[mi] = *reinterpret_cast<const bf16x8*>(&As[aoff[mi][s]]);
#pragma unroll
            for (int ni = 0; ni < 4; ni++)
                bfv[ni] = *reinterpret_cast<const bf16x8*>(&Bs[boff[ni][s]]);
#pragma unroll
            for (int mi = 0; mi < 4; mi++)
#pragma unroll
                for (int ni = 0; ni < 4; ni++)
                    acc[mi][ni] = __builtin_amdgcn_mfma_f32_16x16x32_bf16(af[mi], bfv[ni],
                                                                          acc[mi][ni], 0, 0, 0);
        }
        __syncthreads();
    }

#pragma unroll
    for (int mi = 0; mi < 4; mi++)
#pragma unroll
        for (int ni = 0; ni < 4; ni++)
#pragma unroll
            for (int j = 0; j < 4; j++) {
                int gm = m0 + wm + mi * 16 + quad * 4 + j;
                int gn = n0 + wn + ni * 16 + lr;
                size_t idx = (size_t)gm * N + gn;
                float val = acc[mi][ni][j];
                if constexpr (EPI == 1) {
                    Cf[idx] = val + aux[idx];
                }
            }
}

// ---------------- gemm6 (round-9 config: 16x16 MFMA, round-5 v1 schedule +
// 2D-XCD patches + hoisted incremental staging pointers): 256x256, BK=64, 8 waves,
// 4 phases/K-tile, lookahead-5 staggered staging, ONE vmcnt(2) per K-tile, raw
// barriers, setprio, conflict-free swizzle (verified 0 conflicts).
// EPI 3: QKV fused RoPE + direct-transposed V ; EPI 5: split-K partial ;
// EPI 6: fused W1|W3 interleaved -> silu(a)*b

template <int QM, int QN>
__device__ __forceinline__ void quad_mfma(f32x4 (&acc)[2][2][4][2], const bf16x8 (&af)[4][2],
                                          const bf16x8 (&bf)[2][2]) {
#pragma unroll
    for (int fr = 0; fr < 4; fr++)
#pragma unroll
        for (int fc = 0; fc < 2; fc++)
#pragma unroll
            for (int ks = 0; ks < 2; ks++)
                acc[QM][QN][fr][fc] = __builtin_amdgcn_mfma_f32_16x16x32_bf16(
                    af[fr][ks], bf[fc][ks], acc[QM][QN][fr][fc], 0, 0, 0);
}

template <int EPI>
__launch_bounds__(512, 2) __global__
void gemm6_kernel(const bf16_t* __restrict__ A, const bf16_t* __restrict__ Bt,
                  const bf16_t* __restrict__ auxb, bf16_t* __restrict__ Cb,
                  bf16_t* __restrict__ Cb2, int M, int N, int K, int lda, int ldb) {
    extern __shared__ __align__(16) bf16_t smem[];  // 128 KiB dynamic
    bf16_t* smA = smem;           // [2 buf][2 half][8192]
    bf16_t* smB = smem + 32768;   // [2 buf][2 half][8192]
    const int t = threadIdx.x;
    const int wave = t >> 6, lane = t & 63;
    const int lr = lane & 15, quad = lane >> 4;
    const int rowgrp = wave >> 2;
    const int colgrp = wave & 3;
    const int cg1 = colgrp & 1, cg2 = colgrp >> 1;

    const int gx = gridDim.x, gy = gridDim.y;
    const int nwg = gx * gy;
    const int lin = blockIdx.y * gx + blockIdx.x;
    // HW: XCD = lin % 8 (round-robin). Per-XCD 2D patches keep working set < L2.
    int m0t, n0t;
    if (gy == 32) {
        // W13 (16m x 32n): supergroup 256 = 8m x 32n; XCD grid 2m x 4n; patch 4m x 8n.
        int s = lin >> 8, r = lin & 255, x = r & 7, j = r >> 3;
        m0t = s * 8 + (x & 1) * 4 + (j >> 3);
        n0t = (x >> 1) * 8 + (j & 7);
    } else if (gy == 12) {
        // QKV (16m x 12n, 192 blocks all-resident): XCD grid 4m x 2n; patch 4m x 6n.
        int x = lin & 7, j = lin >> 3;
        m0t = (x & 3) * 4 + j / 6;
        n0t = (x >> 2) * 6 + j % 6;
    } else {
        const int qch = nwg >> 3;
        const int sw = (lin & 7) * qch + (lin >> 3);
        m0t = sw / gy;
        n0t = sw % gy;
    }
    const int m0 = m0t * 256;
    const int n0 = n0t * 256;
    const int koff = blockIdx.z * K;

    const bf16_t* Ag = A + (size_t)m0 * lda + koff;
    const bf16_t* Bg = Bt + (size_t)n0 * ldb + koff;

    // hoisted per-thread staging state: 4 halves x 2 loads, incremental (+64/use)
    const int li0 = (wave * 2 + 0) * 64 + lane;
    const int li1 = (wave * 2 + 1) * 64 + lane;
    const int r0s = li0 >> 3, c0s = ((li0 & 7) ^ (r0s & 7)) << 3;
    const int r1s = li1 >> 3, c1s = ((li1 & 7) ^ (r1s & 7)) << 3;
    const bf16_t* pA0[2] = {Ag + (size_t)r0s * lda + c0s, Ag + (size_t)r1s * lda + c1s};
    const bf16_t* pA1[2] = {pA0[0] + (size_t)128 * lda, pA0[1] + (size_t)128 * lda};
    const bf16_t* pB0[2] = {Bg + (size_t)r0s * ldb + c0s, Bg + (size_t)r1s * ldb + c1s};
    const bf16_t* pB1[2] = {pB0[0] + (size_t)128 * ldb, pB0[1] + (size_t)128 * ldb};
    const int dl0 = (wave * 2 + 0) * 512;
    const int dl1 = (wave * 2 + 1) * 512;

#define STG(P, LBASE)                          \
    do {                                       \
        gl2lds16(P[0], (LBASE) + dl0);         \
        P[0] += 64;                            \
        gl2lds16(P[1], (LBASE) + dl1);         \
        P[1] += 64;                            \
    } while (0)

    int aoff[4][2], boff[2][2];
#pragma unroll
    for (int fr = 0; fr < 4; fr++)
#pragma unroll
        for (int ks = 0; ks < 2; ks++) {
            int ra = rowgrp * 64 + fr * 16 + lr;
            aoff[fr][ks] = ra * 64 + (((ks * 4 + quad) ^ (ra & 7)) << 3);
        }
#pragma unroll
    for (int fc = 0; fc < 2; fc++)
#pragma unroll
        for (int ks = 0; ks < 2; ks++) {
            int rb = cg1 * 64 + cg2 * 16 + fc * 32 + lr;
            boff[fc][ks] = rb * 64 + (((ks * 4 + quad) ^ (rb & 7)) << 3);
        }

    f32x4 acc[2][2][4][2];
#pragma unroll
    for (int qm = 0; qm < 2; qm++)
#pragma unroll
        for (int qn = 0; qn < 2; qn++)
#pragma unroll
            for (int fr = 0; fr < 4; fr++)
#pragma unroll
                for (int fc = 0; fc < 2; fc++) acc[qm][qn][fr][fc] = 0.f;

    const int NT = K >> 6;

    STG(pA0, smA);
    STG(pB0, smB);
    STG(pB1, smB + 8192);
    STG(pA1, smA + 8192);
    if (NT > 1) {
        STG(pA0, smA + 16384);
        __asm__ __volatile__("s_waitcnt vmcnt(2)" ::: "memory");
    } else {
        __asm__ __volatile__("s_waitcnt vmcnt(0)" ::: "memory");
    }
    block_sync();

    bf16x8 af[4][2], bf0[2][2], bf1[2][2];

    for (int tt = 0; tt < NT; ++tt) {
        const int cur = tt & 1, nxt = cur ^ 1;
        const bf16_t* A0b = smA + cur * 16384;
        const bf16_t* A1b = A0b + 8192;
        const bf16_t* B0b = smB + cur * 16384;
        const bf16_t* B1b = B0b + 8192;
        bf16_t* sAn = smA + nxt * 16384;
        bf16_t* sBn = smB + nxt * 16384;
        bf16_t* sAc = smA + cur * 16384;
        const bool pf1 = (tt + 1 < NT);
        const bool pf2 = (tt + 2 < NT);

        // ---- ph0
#pragma unroll
        for (int fr = 0; fr < 4; fr++)
#pragma unroll
            for (int ks = 0; ks < 2; ks++)
                af[fr][ks] = *reinterpret_cast<const bf16x8*>(A0b + aoff[fr][ks]);
#pragma unroll
        for (int fc = 0; fc < 2; fc++)
#pragma unroll
            for (int ks = 0; ks < 2; ks++)
                bf0[fc][ks] = *reinterpret_cast<const bf16x8*>(B0b + boff[fc][ks]);
        if (pf1) STG(pB0, sBn);
        block_sync();
        __asm__ __volatile__("s_waitcnt lgkmcnt(0)" ::: "memory");
        __builtin_amdgcn_sched_barrier(0);
        __builtin_amdgcn_s_setprio(1);
        quad_mfma<0, 0>(acc, af, bf0);
        __builtin_amdgcn_s_setprio(0);
        block_sync();

        // ---- ph1
#pragma unroll
        for (int fc = 0; fc < 2; fc++)
#pragma unroll
            for (int ks = 0; ks < 2; ks++)
                bf1[fc][ks] = *reinterpret_cast<const bf16x8*>(B1b + boff[fc][ks]);
        if (pf1) STG(pB1, sBn + 8192);
        block_sync();
        __asm__ __volatile__("s_waitcnt lgkmcnt(0)" ::: "memory");
        __builtin_amdgcn_sched_barrier(0);
        __builtin_amdgcn_s_setprio(1);
        quad_mfma<0, 1>(acc, af, bf1);
        __builtin_amdgcn_s_setprio(0);
        block_sync();

        // ---- ph2
#pragma unroll
        for (int fr = 0; fr < 4; fr++)
#pragma unroll
            for (int ks = 0; ks < 2; ks++)
                af[fr][ks] = *reinterpret_cast<const bf16x8*>(A1b + aoff[fr][ks]);
        if (pf1) STG(pA1, sAn + 8192);
        block_sync();
        __asm__ __volatile__("s_waitcnt lgkmcnt(0)" ::: "memory");
        __builtin_amdgcn_sched_barrier(0);
        __builtin_amdgcn_s_setprio(1);
        quad_mfma<1, 1>(acc, af, bf1);
        __builtin_amdgcn_s_setprio(0);
        block_sync();

        // ---- ph3
        if (pf2) STG(pA0, sAc);
        __builtin_amdgcn_s_setprio(1);
        quad_mfma<1, 0>(acc, af, bf0);
        __builtin_amdgcn_s_setprio(0);
        __asm__ __volatile__("s_waitcnt vmcnt(2)" ::: "memory");
        block_sync();
    }
#undef STG

    // C/D 16x16 layout: col=lane&15, row=quad*4+reg
    if constexpr (EPI == 3) {
        if (n0 < 2048) {
            const float kfreq = -0.41524101186f;  // -log2(10000)/32
            const int d = cg2 * 16 + lr;          // head-dim of fc=0 element, in [0,32)
            const float freq = exp2f((float)d * kfreq);
#pragma unroll
            for (int qm = 0; qm < 2; qm++)
#pragma unroll
                for (int qn = 0; qn < 2; qn++) {
                    const int gnb = n0 + qn * 128 + cg1 * 64;
#pragma unroll
                    for (int fr = 0; fr < 4; fr++)
#pragma unroll
                        for (int j = 0; j < 4; j++) {
                            int gm = m0 + qm * 128 + rowgrp * 64 + fr * 16 + quad * 4 + j;
                            float pos = (float)(gm & 2047);
                            float ang = pos * freq;
                            float sn, cs;
                            __sincosf(ang, &sn, &cs);
                            float x1 = acc[qm][qn][fr][0][j];
                            float x2 = acc[qm][qn][fr][1][j];
                            size_t idx = (size_t)gm * N + gnb + d;
                            Cb[idx] = (bf16_t)(x1 * cs - x2 * sn);
                            Cb[idx + 32] = (bf16_t)(x2 * cs + x1 * sn);
                        }
                }
        } else {
            // V columns: write direct-transposed into vt [B,H,64,S], packed 4 rows (s)
#pragma unroll
            for (int qm = 0; qm < 2; qm++)
#pragma unroll
                for (int qn = 0; qn < 2; qn++)
#pragma unroll
                    for (int fr = 0; fr < 4; fr++)
#pragma unroll
                        for (int fc = 0; fc < 2; fc++) {
                            int gmb = m0 + qm * 128 + rowgrp * 64 + fr * 16 + quad * 4;
                            int vcol = (n0 - 2048) + qn * 128 + cg1 * 64 + cg2 * 16 + fc * 32 + lr;
                            int hh = vcol >> 6, dd = vcol & 63;
                            int bb2 = gmb >> 11, ss = gmb & 2047;
                            bf16x4 pk;
#pragma unroll
                            for (int j = 0; j < 4; j++) pk[j] = (bf16_t)acc[qm][qn][fr][fc][j];
                            *reinterpret_cast<bf16x4*>(
                                &Cb2[(((size_t)(bb2 * 16 + hh)) * 64 + dd) * 2048 + ss]) = pk;
                        }
        }
    } else if constexpr (EPI == 6) {
        // fused W1|W3: qn=0 -> gate a (W1), qn=1 -> b (W3); out col ld = N/2
        const int No = N >> 1;
#pragma unroll
        for (int qm = 0; qm < 2; qm++)
#pragma unroll
            for (int fr = 0; fr < 4; fr++)
#pragma unroll
                for (int fc = 0; fc < 2; fc++)
#pragma unroll
                    for (int j = 0; j < 4; j++) {
                        int gm = m0 + qm * 128 + rowgrp * 64 + fr * 16 + quad * 4 + j;
                        int c = (n0 >> 1) + cg1 * 64 + cg2 * 16 + fc * 32 + lr;
                        float a = acc[qm][0][fr][fc][j];
                        float bv = acc[qm][1][fr][fc][j];
                        float sl = a / (1.0f + __expf(-a));
                        Cb[(size_t)gm * No + c] = (bf16_t)(sl * bv);
                    }
    } else {
        size_t outoff = (EPI == 5) ? (size_t)blockIdx.z * M * N : 0;
#pragma unroll
        for (int qm = 0; qm < 2; qm++)
#pragma unroll
            for (int qn = 0; qn < 2; qn++)
#pragma unroll
                for (int fr = 0; fr < 4; fr++)
#pragma unroll
                    for (int fc = 0; fc < 2; fc++)
#pragma unroll
                        for (int j = 0; j < 4; j++) {
                            int gm = m0 + qm * 128 + rowgrp * 64 + fr * 16 + quad * 4 + j;
                            int gn = n0 + qn * 128 + cg1 * 64 + cg2 * 16 + fc * 32 + lr;
                            size_t idx = (size_t)gm * N + gn;
                            float val = acc[qm][qn][fr][fc][j];
                            if constexpr (EPI == 5) {
                                Cb[outoff + idx] = (bf16_t)val;
                            } else {
                                Cb[idx] = (bf16_t)val;
                            }
                        }
    }
}

// ---------------- split-K reduce + residual (widened: 8 elems/thread, bf16x8 loads) ----
__global__ void reduce4_kernel(const bf16_t* __restrict__ p, const float* __restrict__ hid,
                               float* __restrict__ out, int n8) {
    int i = blockIdx.x * 256 + threadIdx.x;
    if (i >= n8) return;
    size_t i8 = (size_t)i * 8;
    float4 h0 = *reinterpret_cast<const float4*>(hid + i8);
    float4 h1 = *reinterpret_cast<const float4*>(hid + i8 + 4);
    const size_t stride = (size_t)4096 * 1024;
#pragma unroll
    for (int c = 0; c < 4; c++) {
        bf16x8 a = *reinterpret_cast<const bf16x8*>(p + c * stride + i8);
        h0.x += (float)a[0];
        h0.y += (float)a[1];
        h0.z += (float)a[2];
        h0.w += (float)a[3];
        h1.x += (float)a[4];
        h1.y += (float)a[5];
        h1.z += (float)a[6];
        h1.w += (float)a[7];
    }
    *reinterpret_cast<float4*>(out + i8) = h0;
    *reinterpret_cast<float4*>(out + i8 + 4) = h1;
}

// ---------------- MFMA sliding-window attention (17 K-tiles) ----------------
#define PSTR 40
#define QKVS 3072
__global__ __launch_bounds__(256, 2) void attn_kernel(const bf16_t* __restrict__ qkv,
                                                      const bf16_t* __restrict__ vt,
                                                      bf16_t* __restrict__ ctx, int S) {
    __shared__ __align__(16) bf16_t Pbuf[4][16 * PSTR];
    int t = threadIdx.x;
    int wave = t >> 6, lane = t & 63;
    int col = lane & 15, quad = lane >> 4;
    int h = blockIdx.y, b = blockIdx.z;
    int q0 = blockIdx.x * 64 + wave * 16;

    const bf16_t* qrow = qkv + (size_t)(b * S + q0 + col) * QKVS + h * 64;
    bf16x8 aq0 = *reinterpret_cast<const bf16x8*>(qrow + quad * 8);
    bf16x8 aq1 = *reinterpret_cast<const bf16x8*>(qrow + 32 + quad * 8);

    int jbase = q0 - 256;
    f32x4 sc[17];
#pragma unroll
    for (int kt = 0; kt < 17; kt++) {
        int j = jbase + kt * 16 + col;
        int jc = j < 0 ? 0 : (j > S - 1 ? S - 1 : j);
        const bf16_t* krow = qkv + (size_t)(b * S + jc) * QKVS + 1024 + h * 64;
        bf16x8 bk0 = *reinterpret_cast<const bf16x8*>(krow + quad * 8);
        bf16x8 bk1 = *reinterpret_cast<const bf16x8*>(krow + 32 + quad * 8);
        f32x4 c0 = {0.f, 0.f, 0.f, 0.f};
        c0 = __builtin_amdgcn_mfma_f32_16x16x32_bf16(aq0, bk0, c0, 0, 0, 0);
        c0 = __builtin_amdgcn_mfma_f32_16x16x32_bf16(aq1, bk1, c0, 0, 0, 0);
        sc[kt] = c0;
    }
#pragma unroll
    for (int kt = 0; kt < 17; kt++) {
#pragma unroll
        for (int jj = 0; jj < 4; jj++) {
            int qq = quad * 4 + jj;
            int j = jbase + kt * 16 + col;
            int rel = (q0 + qq) - j;
            bool ok = (j >= 0) && (rel >= 0) && (rel < 256);
            sc[kt][jj] = ok ? sc[kt][jj] * 0.125f : -1e30f;
        }
    }
    float sminv[4];
#pragma unroll
    for (int jj = 0; jj < 4; jj++) {
        float m = -1e30f;
#pragma unroll
        for (int kt = 0; kt < 17; kt++) m = fmaxf(m, sc[kt][jj]);
#pragma unroll
        for (int o = 1; o < 16; o <<= 1) m = fmaxf(m, __shfl_xor(m, o));
        float s = 0.f;
#pragma unroll
        for (int kt = 0; kt < 17; kt++) {
            float p = __expf(sc[kt][jj] - m);
            sc[kt][jj] = p;
            s += p;
        }
#pragma unroll
        for (int o = 1; o < 16; o <<= 1) s += __shfl_xor(s, o);
        sminv[jj] = 1.0f / s;
    }
    f32x4 o[4];
#pragma unroll
    for (int n = 0; n < 4; n++) o[n] = 0.f;
    bf16_t* myP = Pbuf[wave];
    const bf16_t* vplane = vt + ((size_t)(b * 16 + h)) * 64 * S;
#pragma unroll
    for (int c = 0; c < 9; c++) {
#pragma unroll
        for (int half = 0; half < 2; half++) {
            int kt = 2 * c + half;
#pragma unroll
            for (int jj = 0; jj < 4; jj++) {
                int qq = quad * 4 + jj;
                bf16_t pv = (kt < 17) ? (bf16_t)(sc[kt < 17 ? kt : 0][jj] * sminv[jj])
                                      : (bf16_t)0.f;
                myP[qq * PSTR + half * 16 + col] = pv;
            }
        }
        bf16x8 ap = *reinterpret_cast<const bf16x8*>(myP + col * PSTR + quad * 8);
        int key0 = jbase + c * 32 + quad * 8;
        int kc = key0 < 0 ? 0 : (key0 > S - 8 ? S - 8 : key0);
#pragma unroll
        for (int n = 0; n < 4; n++) {
            bf16x8 bv = *reinterpret_cast<const bf16x8*>(vplane + ((size_t)(n * 16 + col)) * S + kc);
            o[n] = __builtin_amdgcn_mfma_f32_16x16x32_bf16(ap, bv, o[n], 0, 0, 0);
        }
    }
#pragma unroll
    for (int n = 0; n < 4; n++)
#pragma unroll
        for (int jj = 0; jj < 4; jj++) {
            int qq = quad * 4 + jj;
            ctx[((size_t)(b * S + q0 + qq) * 16 + h) * 64 + n * 16 + col] = (bf16_t)o[n][jj];
        }
}

// ---------------- launch ----------------
extern "C" void kernel_launch(void* const* d_in, const int* in_sizes, int n_in,
                              void* d_out, int out_size, void* d_ws, size_t ws_size,
                              hipStream_t stream) {
    const float* hs   = (const float*)d_in[0];
    const float* wq   = (const float*)d_in[1];
    const float* wk   = (const float*)d_in[2];
    const float* wv   = (const float*)d_in[3];
    const float* wo   = (const float*)d_in[4];
    const float* w1   = (const float*)d_in[5];
    const float* w2   = (const float*)d_in[6];
    const float* w3   = (const float*)d_in[7];
    const float* ln1g = (const float*)d_in[8];
    const float* ln1b = (const float*)d_in[9];
    const float* ln2g = (const float*)d_in[10];
    const float* ln2b = (const float*)d_in[11];
    float* out = (float*)d_out;

    const int B = 2, S = 2048, D = 1024, I = 4096;
    const int BS = B * S;

    char* ws = (char*)d_ws;
    const size_t MB = 1024 * 1024;
    bf16_t* wq_t  = (bf16_t*)(ws + 0 * MB);    // 2MB
    bf16_t* wk_t  = (bf16_t*)(ws + 2 * MB);    // 2MB
    bf16_t* wv_t  = (bf16_t*)(ws + 4 * MB);    // 2MB
    bf16_t* wo_t  = (bf16_t*)(ws + 6 * MB);    // 2MB
    bf16_t* w13_t = (bf16_t*)(ws + 8 * MB);    // 16MB [8192,1024] interleaved
    bf16_t* w2_t  = (bf16_t*)(ws + 24 * MB);   // 8MB
    bf16_t* x_b   = (bf16_t*)(ws + 32 * MB);   // 8MB
    float*  hid   = (float*)(ws + 40 * MB);    // 16MB
    bf16_t* x2_b  = (bf16_t*)(ws + 56 * MB);   // 8MB
    bf16_t* qkvb  = (bf16_t*)(ws + 64 * MB);   // 24MB [BS,3072] (V section unused)
    bf16_t* vt    = (bf16_t*)(ws + 88 * MB);   // 8MB
    bf16_t* ctxb  = (bf16_t*)(ws + 96 * MB);   // 8MB
    bf16_t* hbuf  = (bf16_t*)(ws + 96 * MB);   // 32MB, aliases ctxb (dead post-Wo)
    bf16_t* pker  = (bf16_t*)(ws + 64 * MB);   // 32MB, aliases qkvb/vt (dead post-attn)

    hipFuncSetAttribute(reinterpret_cast<const void*>(&gemm6_kernel<3>),
                        hipFuncAttributeMaxDynamicSharedMemorySize, 131072);
    hipFuncSetAttribute(reinterpret_cast<const void*>(&gemm6_kernel<5>),
                        hipFuncAttributeMaxDynamicSharedMemorySize, 131072);
    hipFuncSetAttribute(reinterpret_cast<const void*>(&gemm6_kernel<6>),
                        hipFuncAttributeMaxDynamicSharedMemorySize, 131072);

    dim3 tb(256);
    dim3 tb6(512);

    // weight prep + LN1 in one launch
    prep_weights_kernel<<<dim3(20480), tb, 0, stream>>>(wq, wk, wv, wo, w1, w3, w2, wq_t, wk_t,
                                                        wv_t, wo_t, w13_t, w2_t, hs, ln1g, ln1b,
                                                        x_b);

    // fused QKV GEMM (RoPE for q,k cols; V written direct-transposed to vt)
    gemm6_kernel<3><<<dim3(BS / 256, 3072 / 256), tb6, 131072, stream>>>(
        x_b, wq_t, nullptr, qkvb, vt, BS, 3072, D, D, D);

    attn_kernel<<<dim3(S / 64, 16, B), tb, 0, stream>>>(qkvb, vt, ctxb, S);

    // Wo + residual (fp32 out)
    gemm4_kernel<1><<<dim3(BS / 128, D / 128), tb, 0, stream>>>(
        ctxb, wo_t, hid, hs, nullptr, nullptr, BS, D, D, D, D);

    ln_kernel<<<BS, tb, 0, stream>>>(hid, ln2g, ln2b, x2_b, D);

    // fused W1|W3 GEMM + silu*mul (interleaved B, no intermediate)
    gemm6_kernel<6><<<dim3(BS / 256, 8192 / 256), tb6, 131072, stream>>>(
        x2_b, w13_t, nullptr, hbuf, nullptr, BS, 8192, D, D, D);

    // W2: split-K x4 (K=4096 -> 4x1024), bf16 partials, then reduce + residual
    gemm6_kernel<5><<<dim3(BS / 256, D / 256, 4), tb6, 131072, stream>>>(
        hbuf, w2_t, nullptr, pker, nullptr, BS, D, 1024, I, I);
    reduce4_kernel<<<dim3(BS * D / 8 / 256), tb, 0, stream>>>(pker, hid, out, BS * D / 8);
}